// Round 8
// baseline (452.209 us; speedup 1.0000x reference)
//
#include <hip/hip_runtime.h>
#include <math.h>

#define DD 128
#define KK 8
#define LN_EPS 1e-5f
#define NORM_EPS 1e-12f

typedef __attribute__((ext_vector_type(8))) short bf16x8;
typedef __attribute__((ext_vector_type(16))) float f32x16;
typedef unsigned int uint;
typedef unsigned short ushort;

// ws layout (bytes):
//   [0, 122880)        wsA: packed bf16 A-frags of W_ext (160x128):
//                      [split(3)][jt(5)][ks(8)][lane(64)][8 bf16]
//   [122880, 123904)   g2b: 128 x {gamma^2, bias} float2
//   [123904, 124032)   scal[32]: 0..7 pk, 8..15 q0k, 16 cg2s, 17 cgbs,
//                      18 cb2s, 19 cs1, 20 ct1, 21 cr1, 22..29 cuk
#define G2B_OFF_F   (122880 / 4)
#define SCAL_OFF_F  (123904 / 4)

// exact 3-way bf16 split with RNE (prep only)
__device__ inline void split3(float x, uint& h, uint& m, uint& l) {
    uint u0 = __float_as_uint(x);
    uint rh = (u0 + 0x7FFFu + ((u0 >> 16) & 1u)) & 0xFFFF0000u;
    float xh = __uint_as_float(rh);
    float r1 = x - xh;
    uint u1 = __float_as_uint(r1);
    uint rm = (u1 + 0x7FFFu + ((u1 >> 16) & 1u)) & 0xFFFF0000u;
    float xm = __uint_as_float(rm);
    float r2 = r1 - xm;
    uint u2 = __float_as_uint(r2);
    uint rl = (u2 + 0x7FFFu + ((u2 >> 16) & 1u));
    h = rh; m = rm; l = rl;
}

// cheap truncating 3-way split (main loop); residuals exact, last limb trunc.
__device__ inline void split3t(float x, uint& h, uint& m, uint& l) {
    uint u0 = __float_as_uint(x);
    float xh = __uint_as_float(u0 & 0xFFFF0000u);
    float r1 = x - xh;
    uint u1 = __float_as_uint(r1);
    float xm = __uint_as_float(u1 & 0xFFFF0000u);
    float r2 = r1 - xm;
    h = u0; m = u1; l = __float_as_uint(r2);
}

__device__ inline uint packhi(uint a1, uint a0) {
    return __builtin_amdgcn_perm(a1, a0, 0x07060302u);
}

__device__ inline void split2packt(float e0, float e1, uint& ph, uint& pm, uint& pl) {
    uint h0, m0, l0, h1, m1, l1;
    split3t(e0, h0, m0, l0);
    split3t(e1, h1, m1, l1);
    ph = packhi(h1, h0);
    pm = packhi(m1, m0);
    pl = packhi(l1, l0);
}

union FragU  { uint4 u; bf16x8 f; };
union AccU16 { f32x16 v; float a[16]; };

// ---------------------------------------------------------------------------
// prep: build W_ext (160x128: 128 W rows + 11 folded + 21 zero), 3-way split,
// pack into 32x32x16 MFMA A-frag layout. grid 40 blocks: bid -> (jt, ks).
// A-frag: lane = m_local + 32*(k_local>>3), elem i = k_local&7.
// Block (jt=4, ks=0) additionally computes the scalar tables (g2b, scal).
// ---------------------------------------------------------------------------
__global__ void l1q_prep(const float* __restrict__ W, const float* __restrict__ b,
                         const float* __restrict__ gamma, const float* __restrict__ beta,
                         const float* __restrict__ cb, ushort* __restrict__ wsA,
                         float* __restrict__ ws)
{
    __shared__ float invn_s[KK];
    __shared__ float we[11][DD];
    __shared__ float wext[32][16];
    const int t = threadIdx.x;          // 256
    const int jt = blockIdx.x >> 3;     // 0..4
    const int ks = blockIdx.x & 7;      // 0..7

    if (jt == 4) {
        if (t < KK) {
            float s = 0.f;
            for (int j = 0; j < DD; ++j) { float v = cb[t * DD + j]; s = fmaf(v, v, s); }
            invn_s[t] = 1.0f / fmaxf(sqrtf(s), NORM_EPS);
        }
        __syncthreads();
        for (int idx = t; idx < 11 * DD; idx += 256) {
            int e = idx / DD, j = idx % DD;
            float g = gamma[j];
            float v;
            if (e == 0)      v = 1.0f;
            else if (e == 1) v = g * g;
            else if (e == 2) v = g * beta[j];
            else             v = cb[(e - 3) * DD + j] * invn_s[e - 3] * g;
            we[e][j] = v;
        }
        __syncthreads();

        if (ks == 0) {                    // scalar tables
            if (t < DD) {
                float g = gamma[t];
                float* g2b = ws + G2B_OFF_F;
                g2b[2 * t]     = g * g;
                g2b[2 * t + 1] = b[t];
            }
            float* scal = ws + SCAL_OFF_F;
            if (t < KK) {
                float in = invn_s[t];
                float p = 0.f, q = 0.f, cu = 0.f;
                for (int j = 0; j < DD; ++j) {
                    float c = cb[t * DD + j] * in;
                    p  = fmaf(c, gamma[j], p);
                    q  = fmaf(c, beta[j], q);
                    cu = fmaf(c * gamma[j], b[j], cu);
                }
                scal[t]      = p;   // pk
                scal[8 + t]  = q;   // q0k
                scal[22 + t] = cu;  // cuk
            }
            if (t == 16) { float s = 0.f; for (int j = 0; j < DD; ++j) { float g = gamma[j]; s = fmaf(g, g, s); } scal[16] = s; }
            if (t == 17) { float s = 0.f; for (int j = 0; j < DD; ++j) s = fmaf(gamma[j], beta[j], s); scal[17] = s; }
            if (t == 18) { float s = 0.f; for (int j = 0; j < DD; ++j) { float v = beta[j]; s = fmaf(v, v, s); } scal[18] = s; }
            if (t == 19) { float s = 0.f; for (int j = 0; j < DD; ++j) s += b[j]; scal[19] = s; }                              // cs1
            if (t == 20) { float s = 0.f; for (int j = 0; j < DD; ++j) s = fmaf(gamma[j] * gamma[j], b[j], s); scal[20] = s; } // ct1
            if (t == 21) { float s = 0.f; for (int j = 0; j < DD; ++j) s = fmaf(gamma[j] * beta[j], b[j], s); scal[21] = s; }  // cr1
        }
    }

    for (int idx = t; idx < 512; idx += 256) {
        int jl = idx >> 4, kk = idx & 15;
        int k = ks * 16 + kk;
        float val;
        if (jt < 4) {
            val = W[(jt * 32 + jl) * DD + k];
        } else if (jl < 11) {
            float s = 0.f;
            for (int j = 0; j < DD; ++j) s = fmaf(we[jl][j], W[j * DD + k], s);
            val = s;
        } else {
            val = 0.f;
        }
        wext[jl][kk] = val;
    }
    __syncthreads();

    for (int idx = t; idx < 512; idx += 256) {
        int jl = idx >> 4, kk = idx & 15;
        int lane = jl + 32 * (kk >> 3);
        int i = kk & 7;
        uint h, m, l;
        split3(wext[jl][kk], h, m, l);
        int base = jt * 8 + ks;
        wsA[(0 * 40 + base) * 512 + lane * 8 + i] = (ushort)(h >> 16);
        wsA[(1 * 40 + base) * 512 + lane * 8 + i] = (ushort)(m >> 16);
        wsA[(2 * 40 + base) * 512 + lane * 8 + i] = (ushort)(l >> 16);
    }
}

// ---------------------------------------------------------------------------
// main: 512 threads = 8 waves, 32 rows/wave, 256 rows/block, grid B/256.
// LDS diet for 2 co-resident blocks/CU (overlap: one block's store drain
// runs under the other's compute):
//   LDS = h,m limb frags of jt 0..3 only -> 64 KB (+ gath/besti/g2b/scal
//   ~13 KB = 79 KB/block; 2x158 KB <= 160 KB/CU).
//   Cold frags (wl for jt 0..3; all 3 limbs of jt 4) are read from GLOBAL
//   wsA per ks (identical addrs across waves/blocks -> L1/L2-hot), with a
//   1-ks-ahead rolling register prefetch that DIES before the epilogue
//   (R7's spill mechanism structurally avoided).
// Arithmetic, split fns, MFMA order, epilogue identical to R4 -> bit-identical.
// x prefetch: R4's proven 2-deep rolling scheme.
// Lane: n = lane&31 (x-row), h = lane>>5 (k-half). C/D row = (reg&3)+8*(reg>>2)+4*h.
// ---------------------------------------------------------------------------
__global__ __launch_bounds__(512, 4)
void l1q_main(const float* __restrict__ x, const ushort* __restrict__ wsA,
              const float* __restrict__ wsf, const float* __restrict__ cb,
              float* __restrict__ out_idx, float* __restrict__ out_soft,
              float* __restrict__ out_emb, float* __restrict__ out_log,
              int B)
{
    __shared__ uint4 Wl4[4096];        // 65536 B: [limb(h,m)][jt0-3*8+ks][lane]
    __shared__ float gath[8][352];     // [wave][n*11 + local], gcd(11,32)=1
    __shared__ int   besti[8][32];
    __shared__ float g2b_s[256];
    __shared__ float scal_s[32];

    const int t = threadIdx.x;
    const int wave = t >> 6;           // 0..7
    const int lane = t & 63;
    const int n = lane & 31;
    const int h = lane >> 5;
    const int rowbase = blockIdx.x * 256 + wave * 32;
    const int row = rowbase + n;

    const float* xp = x + (size_t)row * DD + h * 8;
    // ks=0,1 x buffers issued early: latency hides under W-preload+barrier
    float4 c0a = *(const float4*)(xp + 0);
    float4 c0c = *(const float4*)(xp + 4);
    float4 c1a = *(const float4*)(xp + 16);
    float4 c1c = *(const float4*)(xp + 20);

    const uint4* gW = (const uint4*)wsA;
    // ks=0 cold frags (global, L1/L2-hot): wl jt0..3 (planes 80+jt*8+ks),
    // jt4 h/m/l (planes 32+ks / 72+ks / 112+ks)
    FragU wl0, wl1, wl2, wl3, h4, m4, l4;
    wl0.u = gW[(80 + 0 * 8 + 0) * 64 + lane];
    wl1.u = gW[(80 + 1 * 8 + 0) * 64 + lane];
    wl2.u = gW[(80 + 2 * 8 + 0) * 64 + lane];
    wl3.u = gW[(80 + 3 * 8 + 0) * 64 + lane];
    h4.u  = gW[(32 + 0) * 64 + lane];
    m4.u  = gW[(72 + 0) * 64 + lane];
    l4.u  = gW[(112 + 0) * 64 + lane];

    // LDS preload: 4096 uint4 = h,m limbs of jt0..3 (global planes
    // limb*40 + jt*8+ks for limb 0,1 -> src idx limb*2560 + rem)
    #pragma unroll
    for (int i = 0; i < 8; ++i) {
        int idx = t + i * 512;
        int limb = idx >> 11, rem = idx & 2047;
        Wl4[idx] = gW[limb * 2560 + rem];
    }
    if (t < 256) g2b_s[t] = wsf[G2B_OFF_F + t];
    if (t < 32)  scal_s[t] = wsf[SCAL_OFF_F + t];
    __syncthreads();

    f32x16 acc[5];
    #pragma unroll
    for (int jt = 0; jt < 5; ++jt)
        #pragma unroll
        for (int r = 0; r < 16; ++r) acc[jt][r] = 0.f;

    #pragma unroll
    for (int ks = 0; ks < 8; ++ks) {
        // x prefetch ks+2 (R4 2-deep, clamp tail)
        int kp = (ks < 6) ? ks + 2 : 7;
        float4 pa = *(const float4*)(xp + kp * 16 + 0);
        float4 pc = *(const float4*)(xp + kp * 16 + 4);

        // cold-frag prefetch for ks+1 (clamp tail; redundant last iters L1-hot)
        int kn = (ks < 7) ? ks + 1 : 7;
        FragU nl0, nl1, nl2, nl3, nh4, nm4, nl4;
        nl0.u = gW[(80 + 0 * 8 + kn) * 64 + lane];
        nl1.u = gW[(80 + 1 * 8 + kn) * 64 + lane];
        nl2.u = gW[(80 + 2 * 8 + kn) * 64 + lane];
        nl3.u = gW[(80 + 3 * 8 + kn) * 64 + lane];
        nh4.u = gW[(32 + kn) * 64 + lane];
        nm4.u = gW[(72 + kn) * 64 + lane];
        nl4.u = gW[(112 + kn) * 64 + lane];

        FragU xh, xm, xl;
        split2packt(c0a.x, c0a.y, xh.u.x, xm.u.x, xl.u.x);
        split2packt(c0a.z, c0a.w, xh.u.y, xm.u.y, xl.u.y);
        split2packt(c0c.x, c0c.y, xh.u.z, xm.u.z, xl.u.z);
        split2packt(c0c.z, c0c.w, xh.u.w, xm.u.w, xl.u.w);

        // jt 0..3: wh,wm from LDS; wl from rolled global regs
        #pragma unroll
        for (int jt = 0; jt < 4; ++jt) {
            const int pl = jt * 8 + ks;
            FragU wh, wm;
            wh.u = Wl4[pl * 64 + lane];             // limb h: planes 0..31
            wm.u = Wl4[(32 + pl) * 64 + lane];      // limb m: planes 32..63
            FragU wl = (jt == 0) ? wl0 : (jt == 1) ? wl1 : (jt == 2) ? wl2 : wl3;
            f32x16 c = acc[jt];
            c = __builtin_amdgcn_mfma_f32_32x32x16_bf16(wl.f, xh.f, c, 0, 0, 0);
            c = __builtin_amdgcn_mfma_f32_32x32x16_bf16(wh.f, xl.f, c, 0, 0, 0);
            c = __builtin_amdgcn_mfma_f32_32x32x16_bf16(wm.f, xm.f, c, 0, 0, 0);
            c = __builtin_amdgcn_mfma_f32_32x32x16_bf16(wm.f, xh.f, c, 0, 0, 0);
            c = __builtin_amdgcn_mfma_f32_32x32x16_bf16(wh.f, xm.f, c, 0, 0, 0);
            c = __builtin_amdgcn_mfma_f32_32x32x16_bf16(wh.f, xh.f, c, 0, 0, 0);
            acc[jt] = c;
        }
        // jt 4: all limbs from rolled global regs (same product order)
        {
            f32x16 c = acc[4];
            c = __builtin_amdgcn_mfma_f32_32x32x16_bf16(l4.f, xh.f, c, 0, 0, 0);
            c = __builtin_amdgcn_mfma_f32_32x32x16_bf16(h4.f, xl.f, c, 0, 0, 0);
            c = __builtin_amdgcn_mfma_f32_32x32x16_bf16(m4.f, xm.f, c, 0, 0, 0);
            c = __builtin_amdgcn_mfma_f32_32x32x16_bf16(m4.f, xh.f, c, 0, 0, 0);
            c = __builtin_amdgcn_mfma_f32_32x32x16_bf16(h4.f, xm.f, c, 0, 0, 0);
            c = __builtin_amdgcn_mfma_f32_32x32x16_bf16(h4.f, xh.f, c, 0, 0, 0);
            acc[4] = c;
        }

        // rotate x and cold-frag buffers (register renames under full unroll)
        c0a = c1a; c0c = c1c;
        c1a = pa;  c1c = pc;
        wl0 = nl0; wl1 = nl1; wl2 = nl2; wl3 = nl3;
        h4 = nh4;  m4 = nm4;  l4 = nl4;
    }

    // ---- quadratic sums over true W rows (jt 0..3) ----
    float s2a = 0.f, t2a = 0.f;
    #pragma unroll
    for (int jt = 0; jt < 4; ++jt) {
        AccU16 a; a.v = acc[jt];
        #pragma unroll
        for (int rq = 0; rq < 4; ++rq) {
            int jb = jt * 32 + 8 * rq + 4 * h;
            #pragma unroll
            for (int r = 0; r < 4; ++r) {
                float2 gb = *(const float2*)&g2b_s[2 * (jb + r)];
                float hv = a.a[rq * 4 + r] + gb.y;
                float h2 = hv * hv;
                s2a += h2;
                t2a = fmaf(gb.x, h2, t2a);
            }
        }
    }
    s2a += __shfl_xor(s2a, 32);
    t2a += __shfl_xor(t2a, 32);

    // ---- gather 11 folded linear sums (tile jt=4, locals 0..10) ----
    {
        AccU16 a; a.v = acc[4];
        #pragma unroll
        for (int rq = 0; rq < 4; ++rq) {
            #pragma unroll
            for (int r = 0; r < 4; ++r) {
                int local = r + 8 * rq + 4 * h;
                if (local < 11) gath[wave][n * 11 + local] = a.a[rq * 4 + r];
            }
        }
    }
    __builtin_amdgcn_s_waitcnt(0);   // wave-internal LDS ordering
    const float* gp = &gath[wave][n * 11];

    const float inv128 = 1.0f / 128.0f;
    const float cg2s = scal_s[16], cgbs = scal_s[17], cb2s = scal_s[18];

    float s1  = gp[0] + scal_s[19];
    float t1  = gp[1] + scal_s[20];
    float r1v = gp[2] + scal_s[21];
    float u[KK];
    #pragma unroll
    for (int k = 0; k < KK; ++k) u[k] = gp[3 + k] + scal_s[22 + k];

    float mu = s1 * inv128;
    float var = fmaf(-mu, mu, s2a * inv128);
    float istd = 1.0f / sqrtf(var + LN_EPS);
    float nrm2 = istd * istd * (t2a - 2.f * mu * t1 + mu * mu * cg2s)
               + 2.f * istd * (r1v - mu * cgbs) + cb2s;
    float rinv = 1.0f / fmaxf(sqrtf(fmaxf(nrm2, 0.f)), NORM_EPS);

    float lg[KK];
    #pragma unroll
    for (int k = 0; k < KK; ++k)
        lg[k] = (istd * (u[k] - mu * scal_s[k]) + scal_s[8 + k]) * rinv;

    float mx = lg[0]; int bi = 0;
    #pragma unroll
    for (int k = 1; k < KK; ++k) if (lg[k] > mx) { mx = lg[k]; bi = k; }

    float ex[KK], se = 0.f;
    #pragma unroll
    for (int k = 0; k < KK; ++k) { ex[k] = expf(lg[k] - mx); se += ex[k]; }
    float rse = 1.0f / se;

    const int m = rowbase + n;
    if (h == 0) {
        out_idx[m] = (float)bi;
        besti[wave][n] = bi;
        *(float4*)&out_log[(size_t)m * KK]     = make_float4(lg[0], lg[1], lg[2], lg[3]);
        *(float4*)&out_log[(size_t)m * KK + 4] = make_float4(lg[4], lg[5], lg[6], lg[7]);
    } else {
        *(float4*)&out_soft[(size_t)m * KK]     = make_float4(ex[0] * rse, ex[1] * rse, ex[2] * rse, ex[3] * rse);
        *(float4*)&out_soft[(size_t)m * KK + 4] = make_float4(ex[4] * rse, ex[5] * rse, ex[6] * rse, ex[7] * rse);
    }

    // ---- embedding: emb[row] = codebook[best[row]], coalesced per wave ----
    __builtin_amdgcn_s_waitcnt(0);
    const float4* cb4 = (const float4*)cb;
    float4* eo = (float4*)out_emb;
    #pragma unroll
    for (int i = 0; i < 16; ++i) {
        int f4 = lane + 64 * i;          // 0..1023 over 32 rows x 32 float4
        int rl = f4 >> 5;
        int c  = f4 & 31;
        int k0 = besti[wave][rl];
        eo[(size_t)(rowbase + rl) * 32 + c] = cb4[k0 * 32 + c];
    }
}

extern "C" void kernel_launch(void* const* d_in, const int* in_sizes, int n_in,
                              void* d_out, int out_size, void* d_ws, size_t ws_size,
                              hipStream_t stream) {
    const float* x     = (const float*)d_in[0];
    const float* W     = (const float*)d_in[1];
    const float* b     = (const float*)d_in[2];
    const float* gamma = (const float*)d_in[3];
    const float* beta  = (const float*)d_in[4];
    const float* cb    = (const float*)d_in[5];
    const int B = in_sizes[0] / DD;

    float*  ws  = (float*)d_ws;
    ushort* wsA = (ushort*)d_ws;

    float* out    = (float*)d_out;
    float* o_idx  = out;
    float* o_soft = out + (size_t)B;
    float* o_emb  = out + (size_t)B * (1 + KK);
    float* o_log  = out + (size_t)B * (1 + KK + DD);

    hipLaunchKernelGGL(l1q_prep, dim3(40), dim3(256), 0, stream, W, b, gamma, beta, cb, wsA, ws);
    const int grid = B / 256;   // 1024 blocks of 512 thr: 2 co-resident/CU
    hipLaunchKernelGGL(l1q_main, dim3(grid), dim3(512), 0, stream,
                       x, wsA, ws, cb, o_idx, o_soft, o_emb, o_log, B);
}

// Round 9
// 288.729 us; speedup vs baseline: 1.5662x; 1.5662x over previous
//
#include <hip/hip_runtime.h>
#include <math.h>

#define DD 128
#define KK 8
#define LN_EPS 1e-5f
#define NORM_EPS 1e-12f

typedef __attribute__((ext_vector_type(8))) short bf16x8;
typedef __attribute__((ext_vector_type(16))) float f32x16;
typedef unsigned int uint;
typedef unsigned short ushort;

// ws layout (bytes):
//   [0, 122880)        wsA: packed bf16 A-frags of W_ext (160x128):
//                      [split(3)][jt(5)][ks(8)][lane(64)][8 bf16]
//   [122880, 123904)   g2b: 128 x {gamma^2, bias} float2
//   [123904, 124032)   scal[32]: 0..7 pk, 8..15 q0k, 16 cg2s, 17 cgbs,
//                      18 cb2s, 19 cs1, 20 ct1, 21 cr1, 22..29 cuk
#define G2B_OFF_F   (122880 / 4)
#define SCAL_OFF_F  (123904 / 4)

// exact 3-way bf16 split with RNE (prep only)
__device__ inline void split3(float x, uint& h, uint& m, uint& l) {
    uint u0 = __float_as_uint(x);
    uint rh = (u0 + 0x7FFFu + ((u0 >> 16) & 1u)) & 0xFFFF0000u;
    float xh = __uint_as_float(rh);
    float r1 = x - xh;
    uint u1 = __float_as_uint(r1);
    uint rm = (u1 + 0x7FFFu + ((u1 >> 16) & 1u)) & 0xFFFF0000u;
    float xm = __uint_as_float(rm);
    float r2 = r1 - xm;
    uint u2 = __float_as_uint(r2);
    uint rl = (u2 + 0x7FFFu + ((u2 >> 16) & 1u));
    h = rh; m = rm; l = rl;
}

// cheap truncating 3-way split (main loop); residuals exact, last limb trunc.
__device__ inline void split3t(float x, uint& h, uint& m, uint& l) {
    uint u0 = __float_as_uint(x);
    float xh = __uint_as_float(u0 & 0xFFFF0000u);
    float r1 = x - xh;
    uint u1 = __float_as_uint(r1);
    float xm = __uint_as_float(u1 & 0xFFFF0000u);
    float r2 = r1 - xm;
    h = u0; m = u1; l = __float_as_uint(r2);
}

__device__ inline uint packhi(uint a1, uint a0) {
    return __builtin_amdgcn_perm(a1, a0, 0x07060302u);
}

__device__ inline void split2packt(float e0, float e1, uint& ph, uint& pm, uint& pl) {
    uint h0, m0, l0, h1, m1, l1;
    split3t(e0, h0, m0, l0);
    split3t(e1, h1, m1, l1);
    ph = packhi(h1, h0);
    pm = packhi(m1, m0);
    pl = packhi(l1, l0);
}

union FragU  { uint4 u; bf16x8 f; };
union AccU16 { f32x16 v; float a[16]; };

// ---------------------------------------------------------------------------
// prep: build W_ext (160x128: 128 W rows + 11 folded + 21 zero), 3-way split,
// pack into 32x32x16 MFMA A-frag layout. grid 40 blocks: bid -> (jt, ks).
// A-frag: lane = m_local + 32*(k_local>>3), elem i = k_local&7.
// Block (jt=4, ks=0) additionally computes the scalar tables (g2b, scal).
// ---------------------------------------------------------------------------
__global__ void l1q_prep(const float* __restrict__ W, const float* __restrict__ b,
                         const float* __restrict__ gamma, const float* __restrict__ beta,
                         const float* __restrict__ cb, ushort* __restrict__ wsA,
                         float* __restrict__ ws)
{
    __shared__ float invn_s[KK];
    __shared__ float we[11][DD];
    __shared__ float wext[32][16];
    const int t = threadIdx.x;          // 256
    const int jt = blockIdx.x >> 3;     // 0..4
    const int ks = blockIdx.x & 7;      // 0..7

    if (jt == 4) {
        if (t < KK) {
            float s = 0.f;
            for (int j = 0; j < DD; ++j) { float v = cb[t * DD + j]; s = fmaf(v, v, s); }
            invn_s[t] = 1.0f / fmaxf(sqrtf(s), NORM_EPS);
        }
        __syncthreads();
        for (int idx = t; idx < 11 * DD; idx += 256) {
            int e = idx / DD, j = idx % DD;
            float g = gamma[j];
            float v;
            if (e == 0)      v = 1.0f;
            else if (e == 1) v = g * g;
            else if (e == 2) v = g * beta[j];
            else             v = cb[(e - 3) * DD + j] * invn_s[e - 3] * g;
            we[e][j] = v;
        }
        __syncthreads();

        if (ks == 0) {                    // scalar tables
            if (t < DD) {
                float g = gamma[t];
                float* g2b = ws + G2B_OFF_F;
                g2b[2 * t]     = g * g;
                g2b[2 * t + 1] = b[t];
            }
            float* scal = ws + SCAL_OFF_F;
            if (t < KK) {
                float in = invn_s[t];
                float p = 0.f, q = 0.f, cu = 0.f;
                for (int j = 0; j < DD; ++j) {
                    float c = cb[t * DD + j] * in;
                    p  = fmaf(c, gamma[j], p);
                    q  = fmaf(c, beta[j], q);
                    cu = fmaf(c * gamma[j], b[j], cu);
                }
                scal[t]      = p;   // pk
                scal[8 + t]  = q;   // q0k
                scal[22 + t] = cu;  // cuk
            }
            if (t == 16) { float s = 0.f; for (int j = 0; j < DD; ++j) { float g = gamma[j]; s = fmaf(g, g, s); } scal[16] = s; }
            if (t == 17) { float s = 0.f; for (int j = 0; j < DD; ++j) s = fmaf(gamma[j], beta[j], s); scal[17] = s; }
            if (t == 18) { float s = 0.f; for (int j = 0; j < DD; ++j) { float v = beta[j]; s = fmaf(v, v, s); } scal[18] = s; }
            if (t == 19) { float s = 0.f; for (int j = 0; j < DD; ++j) s += b[j]; scal[19] = s; }                              // cs1
            if (t == 20) { float s = 0.f; for (int j = 0; j < DD; ++j) s = fmaf(gamma[j] * gamma[j], b[j], s); scal[20] = s; } // ct1
            if (t == 21) { float s = 0.f; for (int j = 0; j < DD; ++j) s = fmaf(gamma[j] * beta[j], b[j], s); scal[21] = s; }  // cr1
        }
    }

    for (int idx = t; idx < 512; idx += 256) {
        int jl = idx >> 4, kk = idx & 15;
        int k = ks * 16 + kk;
        float val;
        if (jt < 4) {
            val = W[(jt * 32 + jl) * DD + k];
        } else if (jl < 11) {
            float s = 0.f;
            for (int j = 0; j < DD; ++j) s = fmaf(we[jl][j], W[j * DD + k], s);
            val = s;
        } else {
            val = 0.f;
        }
        wext[jl][kk] = val;
    }
    __syncthreads();

    for (int idx = t; idx < 512; idx += 256) {
        int jl = idx >> 4, kk = idx & 15;
        int lane = jl + 32 * (kk >> 3);
        int i = kk & 7;
        uint h, m, l;
        split3(wext[jl][kk], h, m, l);
        int base = jt * 8 + ks;
        wsA[(0 * 40 + base) * 512 + lane * 8 + i] = (ushort)(h >> 16);
        wsA[(1 * 40 + base) * 512 + lane * 8 + i] = (ushort)(m >> 16);
        wsA[(2 * 40 + base) * 512 + lane * 8 + i] = (ushort)(l >> 16);
    }
}

// ---------------------------------------------------------------------------
// main: 1024 threads = 16 waves, 32 rows/wave, 512 rows/block, grid B/512.
// The R4-proven pipeline (best measured: 93.4 us main), with ONE change:
// epilogue waits are lgkmcnt-only (0xc07f) instead of full drains, so waves
// never serialize on their own output-store completion or on the dead tail
// prefetch loads. Both LDS dependences (gath, besti) are lgkm-covered.
// D[j_ext][n] = W_ext x x^T via 6-product split-bf16 mfma_32x32x16.
// Lane: n = lane&31 (x-row), h = lane>>5 (k-half). C/D row = (reg&3)+8*(reg>>2)+4*h.
// x prefetch: 2 ks-iterations deep (3 rotating float4-pair buffers).
// ---------------------------------------------------------------------------
__global__ __launch_bounds__(1024, 4)
void l1q_main(const float* __restrict__ x, const ushort* __restrict__ wsA,
              const float* __restrict__ wsf, const float* __restrict__ cb,
              float* __restrict__ out_idx, float* __restrict__ out_soft,
              float* __restrict__ out_emb, float* __restrict__ out_log,
              int B)
{
    __shared__ uint4 Wl4[7680];        // 122880 B packed W_ext frags
    __shared__ float gath[16][352];    // [wave][n*11 + local], gcd(11,32)=1
    __shared__ int   besti[16][32];
    __shared__ float g2b_s[256];
    __shared__ float scal_s[32];

    const int t = threadIdx.x;
    const int wave = t >> 6;
    const int lane = t & 63;
    const int n = lane & 31;
    const int h = lane >> 5;
    const int rowbase = blockIdx.x * 512 + wave * 32;
    const int row = rowbase + n;

    const float* xp = x + (size_t)row * DD + h * 8;
    // ks=0 and ks=1 buffers issued early: latency hides under W-preload+barrier
    float4 c0a = *(const float4*)(xp + 0);
    float4 c0c = *(const float4*)(xp + 4);
    float4 c1a = *(const float4*)(xp + 16);
    float4 c1c = *(const float4*)(xp + 20);

    {
        const uint4* src = (const uint4*)wsA;
        #pragma unroll
        for (int i = 0; i < 8; ++i) {
            int idx = t + i * 1024;
            if (idx < 7680) Wl4[idx] = src[idx];
        }
    }
    if (t < 256) g2b_s[t] = wsf[G2B_OFF_F + t];
    if (t < 32)  scal_s[t] = wsf[SCAL_OFF_F + t];
    __syncthreads();

    f32x16 acc[5];
    #pragma unroll
    for (int jt = 0; jt < 5; ++jt)
        #pragma unroll
        for (int r = 0; r < 16; ++r) acc[jt][r] = 0.f;

    #pragma unroll
    for (int ks = 0; ks < 8; ++ks) {
        // prefetch ks+2 (2-deep); dead-safe: clamp to ks=7's chunk for tail
        int kp = (ks < 6) ? ks + 2 : 7;
        float4 pa = *(const float4*)(xp + kp * 16 + 0);
        float4 pc = *(const float4*)(xp + kp * 16 + 4);

        FragU xh, xm, xl;
        split2packt(c0a.x, c0a.y, xh.u.x, xm.u.x, xl.u.x);
        split2packt(c0a.z, c0a.w, xh.u.y, xm.u.y, xl.u.y);
        split2packt(c0c.x, c0c.y, xh.u.z, xm.u.z, xl.u.z);
        split2packt(c0c.z, c0c.w, xh.u.w, xm.u.w, xl.u.w);

        #pragma unroll
        for (int jt = 0; jt < 5; ++jt) {
            const int pl = jt * 8 + ks;
            FragU wh, wm, wl;
            wh.u = Wl4[(0 * 40 + pl) * 64 + lane];
            wm.u = Wl4[(1 * 40 + pl) * 64 + lane];
            wl.u = Wl4[(2 * 40 + pl) * 64 + lane];
            f32x16 c = acc[jt];
            c = __builtin_amdgcn_mfma_f32_32x32x16_bf16(wl.f, xh.f, c, 0, 0, 0);
            c = __builtin_amdgcn_mfma_f32_32x32x16_bf16(wh.f, xl.f, c, 0, 0, 0);
            c = __builtin_amdgcn_mfma_f32_32x32x16_bf16(wm.f, xm.f, c, 0, 0, 0);
            c = __builtin_amdgcn_mfma_f32_32x32x16_bf16(wm.f, xh.f, c, 0, 0, 0);
            c = __builtin_amdgcn_mfma_f32_32x32x16_bf16(wh.f, xm.f, c, 0, 0, 0);
            c = __builtin_amdgcn_mfma_f32_32x32x16_bf16(wh.f, xh.f, c, 0, 0, 0);
            acc[jt] = c;
        }
        // rotate: cur <- next, next <- prefetched
        c0a = c1a; c0c = c1c;
        c1a = pa;  c1c = pc;
    }

    // ---- quadratic sums over true W rows (jt 0..3) ----
    float s2a = 0.f, t2a = 0.f;
    #pragma unroll
    for (int jt = 0; jt < 4; ++jt) {
        AccU16 a; a.v = acc[jt];
        #pragma unroll
        for (int rq = 0; rq < 4; ++rq) {
            int jb = jt * 32 + 8 * rq + 4 * h;
            #pragma unroll
            for (int r = 0; r < 4; ++r) {
                float2 gb = *(const float2*)&g2b_s[2 * (jb + r)];
                float hv = a.a[rq * 4 + r] + gb.y;
                float h2 = hv * hv;
                s2a += h2;
                t2a = fmaf(gb.x, h2, t2a);
            }
        }
    }
    s2a += __shfl_xor(s2a, 32);
    t2a += __shfl_xor(t2a, 32);

    // ---- gather 11 folded linear sums (tile jt=4, locals 0..10) ----
    {
        AccU16 a; a.v = acc[4];
        #pragma unroll
        for (int rq = 0; rq < 4; ++rq) {
            #pragma unroll
            for (int r = 0; r < 4; ++r) {
                int local = r + 8 * rq + 4 * h;
                if (local < 11) gath[wave][n * 11 + local] = a.a[rq * 4 + r];
            }
        }
    }
    // lgkmcnt(0) only (vmcnt=63, expcnt=7): wave-internal LDS ordering
    // without draining the dead tail prefetch loads
    __builtin_amdgcn_s_waitcnt(0xc07f);
    const float* gp = &gath[wave][n * 11];

    const float inv128 = 1.0f / 128.0f;
    const float cg2s = scal_s[16], cgbs = scal_s[17], cb2s = scal_s[18];

    float s1  = gp[0] + scal_s[19];
    float t1  = gp[1] + scal_s[20];
    float r1v = gp[2] + scal_s[21];
    float u[KK];
    #pragma unroll
    for (int k = 0; k < KK; ++k) u[k] = gp[3 + k] + scal_s[22 + k];

    float mu = s1 * inv128;
    float var = fmaf(-mu, mu, s2a * inv128);
    float istd = 1.0f / sqrtf(var + LN_EPS);
    float nrm2 = istd * istd * (t2a - 2.f * mu * t1 + mu * mu * cg2s)
               + 2.f * istd * (r1v - mu * cgbs) + cb2s;
    float rinv = 1.0f / fmaxf(sqrtf(fmaxf(nrm2, 0.f)), NORM_EPS);

    float lg[KK];
    #pragma unroll
    for (int k = 0; k < KK; ++k)
        lg[k] = (istd * (u[k] - mu * scal_s[k]) + scal_s[8 + k]) * rinv;

    float mx = lg[0]; int bi = 0;
    #pragma unroll
    for (int k = 1; k < KK; ++k) if (lg[k] > mx) { mx = lg[k]; bi = k; }

    float ex[KK], se = 0.f;
    #pragma unroll
    for (int k = 0; k < KK; ++k) { ex[k] = expf(lg[k] - mx); se += ex[k]; }
    float rse = 1.0f / se;

    const int m = rowbase + n;
    if (h == 0) {
        out_idx[m] = (float)bi;
        besti[wave][n] = bi;
        *(float4*)&out_log[(size_t)m * KK]     = make_float4(lg[0], lg[1], lg[2], lg[3]);
        *(float4*)&out_log[(size_t)m * KK + 4] = make_float4(lg[4], lg[5], lg[6], lg[7]);
    } else {
        *(float4*)&out_soft[(size_t)m * KK]     = make_float4(ex[0] * rse, ex[1] * rse, ex[2] * rse, ex[3] * rse);
        *(float4*)&out_soft[(size_t)m * KK + 4] = make_float4(ex[4] * rse, ex[5] * rse, ex[6] * rse, ex[7] * rse);
    }

    // ---- embedding: emb[row] = codebook[best[row]], coalesced per wave ----
    // lgkmcnt(0) only: besti visibility; do NOT wait on own output stores
    __builtin_amdgcn_s_waitcnt(0xc07f);
    const float4* cb4 = (const float4*)cb;
    float4* eo = (float4*)out_emb;
    #pragma unroll
    for (int i = 0; i < 16; ++i) {
        int f4 = lane + 64 * i;          // 0..1023 over 32 rows x 32 float4
        int rl = f4 >> 5;
        int c  = f4 & 31;
        int k0 = besti[wave][rl];
        eo[(size_t)(rowbase + rl) * 32 + c] = cb4[k0 * 32 + c];
    }
}

extern "C" void kernel_launch(void* const* d_in, const int* in_sizes, int n_in,
                              void* d_out, int out_size, void* d_ws, size_t ws_size,
                              hipStream_t stream) {
    const float* x     = (const float*)d_in[0];
    const float* W     = (const float*)d_in[1];
    const float* b     = (const float*)d_in[2];
    const float* gamma = (const float*)d_in[3];
    const float* beta  = (const float*)d_in[4];
    const float* cb    = (const float*)d_in[5];
    const int B = in_sizes[0] / DD;

    float*  ws  = (float*)d_ws;
    ushort* wsA = (ushort*)d_ws;

    float* out    = (float*)d_out;
    float* o_idx  = out;
    float* o_soft = out + (size_t)B;
    float* o_emb  = out + (size_t)B * (1 + KK);
    float* o_log  = out + (size_t)B * (1 + KK + DD);

    hipLaunchKernelGGL(l1q_prep, dim3(40), dim3(256), 0, stream, W, b, gamma, beta, cb, wsA, ws);
    const int grid = B / 512;
    hipLaunchKernelGGL(l1q_main, dim3(grid), dim3(1024), 0, stream,
                       x, wsA, ws, cb, o_idx, o_soft, o_emb, o_log, B);
}

// Round 11
// 284.605 us; speedup vs baseline: 1.5889x; 1.0145x over previous
//
#include <hip/hip_runtime.h>
#include <math.h>

#define DD 128
#define KK 8
#define LN_EPS 1e-5f
#define NORM_EPS 1e-12f

typedef __attribute__((ext_vector_type(8))) short bf16x8;
typedef __attribute__((ext_vector_type(16))) float f32x16;
typedef __attribute__((ext_vector_type(4))) float f32x4;
typedef unsigned int uint;
typedef unsigned short ushort;

// ws layout (bytes):
//   [0, 122880)        wsA: packed bf16 A-frags of W_ext (160x128):
//                      [split(3)][jt(5)][ks(8)][lane(64)][8 bf16]
//   [122880, 123904)   g2b: 128 x {gamma^2, bias} float2
//   [123904, 124032)   scal[32]: 0..7 pk, 8..15 q0k, 16 cg2s, 17 cgbs,
//                      18 cb2s, 19 cs1, 20 ct1, 21 cr1, 22..29 cuk
#define G2B_OFF_F   (122880 / 4)
#define SCAL_OFF_F  (123904 / 4)

// exact 3-way bf16 split with RNE (prep only)
__device__ inline void split3(float x, uint& h, uint& m, uint& l) {
    uint u0 = __float_as_uint(x);
    uint rh = (u0 + 0x7FFFu + ((u0 >> 16) & 1u)) & 0xFFFF0000u;
    float xh = __uint_as_float(rh);
    float r1 = x - xh;
    uint u1 = __float_as_uint(r1);
    uint rm = (u1 + 0x7FFFu + ((u1 >> 16) & 1u)) & 0xFFFF0000u;
    float xm = __uint_as_float(rm);
    float r2 = r1 - xm;
    uint u2 = __float_as_uint(r2);
    uint rl = (u2 + 0x7FFFu + ((u2 >> 16) & 1u));
    h = rh; m = rm; l = rl;
}

// cheap truncating 3-way split (main loop); residuals exact, last limb trunc.
__device__ inline void split3t(float x, uint& h, uint& m, uint& l) {
    uint u0 = __float_as_uint(x);
    float xh = __uint_as_float(u0 & 0xFFFF0000u);
    float r1 = x - xh;
    uint u1 = __float_as_uint(r1);
    float xm = __uint_as_float(u1 & 0xFFFF0000u);
    float r2 = r1 - xm;
    h = u0; m = u1; l = __float_as_uint(r2);
}

__device__ inline uint packhi(uint a1, uint a0) {
    return __builtin_amdgcn_perm(a1, a0, 0x07060302u);
}

__device__ inline void split2packt(float e0, float e1, uint& ph, uint& pm, uint& pl) {
    uint h0, m0, l0, h1, m1, l1;
    split3t(e0, h0, m0, l0);
    split3t(e1, h1, m1, l1);
    ph = packhi(h1, h0);
    pm = packhi(m1, m0);
    pl = packhi(l1, l0);
}

// nontemporal 16B store via native ext_vector type (same layout as float4)
__device__ inline void nt_store4(float* p, float a, float b, float c, float d) {
    f32x4 v; v.x = a; v.y = b; v.z = c; v.w = d;
    __builtin_nontemporal_store(v, (f32x4*)p);
}
__device__ inline void nt_copy4(float* p, const float4* s) {
    __builtin_nontemporal_store(*(const f32x4*)s, (f32x4*)p);
}

union FragU  { uint4 u; bf16x8 f; };
union AccU16 { f32x16 v; float a[16]; };

// ---------------------------------------------------------------------------
// prep: build W_ext (160x128: 128 W rows + 11 folded + 21 zero), 3-way split,
// pack into 32x32x16 MFMA A-frag layout. grid 40 blocks: bid -> (jt, ks).
// A-frag: lane = m_local + 32*(k_local>>3), elem i = k_local&7.
// Block (jt=4, ks=0) additionally computes the scalar tables (g2b, scal).
// ---------------------------------------------------------------------------
__global__ void l1q_prep(const float* __restrict__ W, const float* __restrict__ b,
                         const float* __restrict__ gamma, const float* __restrict__ beta,
                         const float* __restrict__ cb, ushort* __restrict__ wsA,
                         float* __restrict__ ws)
{
    __shared__ float invn_s[KK];
    __shared__ float we[11][DD];
    __shared__ float wext[32][16];
    const int t = threadIdx.x;          // 256
    const int jt = blockIdx.x >> 3;     // 0..4
    const int ks = blockIdx.x & 7;      // 0..7

    if (jt == 4) {
        if (t < KK) {
            float s = 0.f;
            for (int j = 0; j < DD; ++j) { float v = cb[t * DD + j]; s = fmaf(v, v, s); }
            invn_s[t] = 1.0f / fmaxf(sqrtf(s), NORM_EPS);
        }
        __syncthreads();
        for (int idx = t; idx < 11 * DD; idx += 256) {
            int e = idx / DD, j = idx % DD;
            float g = gamma[j];
            float v;
            if (e == 0)      v = 1.0f;
            else if (e == 1) v = g * g;
            else if (e == 2) v = g * beta[j];
            else             v = cb[(e - 3) * DD + j] * invn_s[e - 3] * g;
            we[e][j] = v;
        }
        __syncthreads();

        if (ks == 0) {                    // scalar tables
            if (t < DD) {
                float g = gamma[t];
                float* g2b = ws + G2B_OFF_F;
                g2b[2 * t]     = g * g;
                g2b[2 * t + 1] = b[t];
            }
            float* scal = ws + SCAL_OFF_F;
            if (t < KK) {
                float in = invn_s[t];
                float p = 0.f, q = 0.f, cu = 0.f;
                for (int j = 0; j < DD; ++j) {
                    float c = cb[t * DD + j] * in;
                    p  = fmaf(c, gamma[j], p);
                    q  = fmaf(c, beta[j], q);
                    cu = fmaf(c * gamma[j], b[j], cu);
                }
                scal[t]      = p;   // pk
                scal[8 + t]  = q;   // q0k
                scal[22 + t] = cu;  // cuk
            }
            if (t == 16) { float s = 0.f; for (int j = 0; j < DD; ++j) { float g = gamma[j]; s = fmaf(g, g, s); } scal[16] = s; }
            if (t == 17) { float s = 0.f; for (int j = 0; j < DD; ++j) s = fmaf(gamma[j], beta[j], s); scal[17] = s; }
            if (t == 18) { float s = 0.f; for (int j = 0; j < DD; ++j) { float v = beta[j]; s = fmaf(v, v, s); } scal[18] = s; }
            if (t == 19) { float s = 0.f; for (int j = 0; j < DD; ++j) s += b[j]; scal[19] = s; }                              // cs1
            if (t == 20) { float s = 0.f; for (int j = 0; j < DD; ++j) s = fmaf(gamma[j] * gamma[j], b[j], s); scal[20] = s; } // ct1
            if (t == 21) { float s = 0.f; for (int j = 0; j < DD; ++j) s = fmaf(gamma[j] * beta[j], b[j], s); scal[21] = s; }  // cr1
        }
    }

    for (int idx = t; idx < 512; idx += 256) {
        int jl = idx >> 4, kk = idx & 15;
        int k = ks * 16 + kk;
        float val;
        if (jt < 4) {
            val = W[(jt * 32 + jl) * DD + k];
        } else if (jl < 11) {
            float s = 0.f;
            for (int j = 0; j < DD; ++j) s = fmaf(we[jl][j], W[j * DD + k], s);
            val = s;
        } else {
            val = 0.f;
        }
        wext[jl][kk] = val;
    }
    __syncthreads();

    for (int idx = t; idx < 512; idx += 256) {
        int jl = idx >> 4, kk = idx & 15;
        int lane = jl + 32 * (kk >> 3);
        int i = kk & 7;
        uint h, m, l;
        split3(wext[jl][kk], h, m, l);
        int base = jt * 8 + ks;
        wsA[(0 * 40 + base) * 512 + lane * 8 + i] = (ushort)(h >> 16);
        wsA[(1 * 40 + base) * 512 + lane * 8 + i] = (ushort)(m >> 16);
        wsA[(2 * 40 + base) * 512 + lane * 8 + i] = (ushort)(l >> 16);
    }
}

// ---------------------------------------------------------------------------
// main: 1024 threads = 16 waves, 32 rows/wave, 512 rows/block, grid B/512.
// R4/R9-proven pipeline (93.4 us main) with ONE register-free change: all
// output stores are NONTEMPORAL. Outputs (152 MB) are write-once/never-read;
// streaming them through L2/L3 evicts x (128 MB, the only cross-iteration
// reuse). nt stores keep the dead write data out of the cache hierarchy ->
// x stays L3-resident -> lower FETCH and lower effective x-load latency.
// D[j_ext][n] = W_ext x x^T via 6-product split-bf16 mfma_32x32x16.
// Lane: n = lane&31 (x-row), h = lane>>5 (k-half). C/D row = (reg&3)+8*(reg>>2)+4*h.
// x prefetch: 2 ks-iterations deep (3 rotating float4-pair buffers).
// ---------------------------------------------------------------------------
__global__ __launch_bounds__(1024, 4)
void l1q_main(const float* __restrict__ x, const ushort* __restrict__ wsA,
              const float* __restrict__ wsf, const float* __restrict__ cb,
              float* __restrict__ out_idx, float* __restrict__ out_soft,
              float* __restrict__ out_emb, float* __restrict__ out_log,
              int B)
{
    __shared__ uint4 Wl4[7680];        // 122880 B packed W_ext frags
    __shared__ float gath[16][352];    // [wave][n*11 + local], gcd(11,32)=1
    __shared__ int   besti[16][32];
    __shared__ float g2b_s[256];
    __shared__ float scal_s[32];

    const int t = threadIdx.x;
    const int wave = t >> 6;
    const int lane = t & 63;
    const int n = lane & 31;
    const int h = lane >> 5;
    const int rowbase = blockIdx.x * 512 + wave * 32;
    const int row = rowbase + n;

    const float* xp = x + (size_t)row * DD + h * 8;
    // ks=0 and ks=1 buffers issued early: latency hides under W-preload+barrier
    float4 c0a = *(const float4*)(xp + 0);
    float4 c0c = *(const float4*)(xp + 4);
    float4 c1a = *(const float4*)(xp + 16);
    float4 c1c = *(const float4*)(xp + 20);

    {
        const uint4* src = (const uint4*)wsA;
        #pragma unroll
        for (int i = 0; i < 8; ++i) {
            int idx = t + i * 1024;
            if (idx < 7680) Wl4[idx] = src[idx];
        }
    }
    if (t < 256) g2b_s[t] = wsf[G2B_OFF_F + t];
    if (t < 32)  scal_s[t] = wsf[SCAL_OFF_F + t];
    __syncthreads();

    f32x16 acc[5];
    #pragma unroll
    for (int jt = 0; jt < 5; ++jt)
        #pragma unroll
        for (int r = 0; r < 16; ++r) acc[jt][r] = 0.f;

    #pragma unroll
    for (int ks = 0; ks < 8; ++ks) {
        // prefetch ks+2 (2-deep); dead-safe: clamp to ks=7's chunk for tail
        int kp = (ks < 6) ? ks + 2 : 7;
        float4 pa = *(const float4*)(xp + kp * 16 + 0);
        float4 pc = *(const float4*)(xp + kp * 16 + 4);

        FragU xh, xm, xl;
        split2packt(c0a.x, c0a.y, xh.u.x, xm.u.x, xl.u.x);
        split2packt(c0a.z, c0a.w, xh.u.y, xm.u.y, xl.u.y);
        split2packt(c0c.x, c0c.y, xh.u.z, xm.u.z, xl.u.z);
        split2packt(c0c.z, c0c.w, xh.u.w, xm.u.w, xl.u.w);

        #pragma unroll
        for (int jt = 0; jt < 5; ++jt) {
            const int pl = jt * 8 + ks;
            FragU wh, wm, wl;
            wh.u = Wl4[(0 * 40 + pl) * 64 + lane];
            wm.u = Wl4[(1 * 40 + pl) * 64 + lane];
            wl.u = Wl4[(2 * 40 + pl) * 64 + lane];
            f32x16 c = acc[jt];
            c = __builtin_amdgcn_mfma_f32_32x32x16_bf16(wl.f, xh.f, c, 0, 0, 0);
            c = __builtin_amdgcn_mfma_f32_32x32x16_bf16(wh.f, xl.f, c, 0, 0, 0);
            c = __builtin_amdgcn_mfma_f32_32x32x16_bf16(wm.f, xm.f, c, 0, 0, 0);
            c = __builtin_amdgcn_mfma_f32_32x32x16_bf16(wm.f, xh.f, c, 0, 0, 0);
            c = __builtin_amdgcn_mfma_f32_32x32x16_bf16(wh.f, xm.f, c, 0, 0, 0);
            c = __builtin_amdgcn_mfma_f32_32x32x16_bf16(wh.f, xh.f, c, 0, 0, 0);
            acc[jt] = c;
        }
        // rotate: cur <- next, next <- prefetched
        c0a = c1a; c0c = c1c;
        c1a = pa;  c1c = pc;
    }

    // ---- quadratic sums over true W rows (jt 0..3) ----
    float s2a = 0.f, t2a = 0.f;
    #pragma unroll
    for (int jt = 0; jt < 4; ++jt) {
        AccU16 a; a.v = acc[jt];
        #pragma unroll
        for (int rq = 0; rq < 4; ++rq) {
            int jb = jt * 32 + 8 * rq + 4 * h;
            #pragma unroll
            for (int r = 0; r < 4; ++r) {
                float2 gb = *(const float2*)&g2b_s[2 * (jb + r)];
                float hv = a.a[rq * 4 + r] + gb.y;
                float h2 = hv * hv;
                s2a += h2;
                t2a = fmaf(gb.x, h2, t2a);
            }
        }
    }
    s2a += __shfl_xor(s2a, 32);
    t2a += __shfl_xor(t2a, 32);

    // ---- gather 11 folded linear sums (tile jt=4, locals 0..10) ----
    {
        AccU16 a; a.v = acc[4];
        #pragma unroll
        for (int rq = 0; rq < 4; ++rq) {
            #pragma unroll
            for (int r = 0; r < 4; ++r) {
                int local = r + 8 * rq + 4 * h;
                if (local < 11) gath[wave][n * 11 + local] = a.a[rq * 4 + r];
            }
        }
    }
    // lgkmcnt(0) only (vmcnt=63, expcnt=7): wave-internal LDS ordering
    // without draining the dead tail prefetch loads
    __builtin_amdgcn_s_waitcnt(0xc07f);
    const float* gp = &gath[wave][n * 11];

    const float inv128 = 1.0f / 128.0f;
    const float cg2s = scal_s[16], cgbs = scal_s[17], cb2s = scal_s[18];

    float s1  = gp[0] + scal_s[19];
    float t1  = gp[1] + scal_s[20];
    float r1v = gp[2] + scal_s[21];
    float u[KK];
    #pragma unroll
    for (int k = 0; k < KK; ++k) u[k] = gp[3 + k] + scal_s[22 + k];

    float mu = s1 * inv128;
    float var = fmaf(-mu, mu, s2a * inv128);
    float istd = 1.0f / sqrtf(var + LN_EPS);
    float nrm2 = istd * istd * (t2a - 2.f * mu * t1 + mu * mu * cg2s)
               + 2.f * istd * (r1v - mu * cgbs) + cb2s;
    float rinv = 1.0f / fmaxf(sqrtf(fmaxf(nrm2, 0.f)), NORM_EPS);

    float lg[KK];
    #pragma unroll
    for (int k = 0; k < KK; ++k)
        lg[k] = (istd * (u[k] - mu * scal_s[k]) + scal_s[8 + k]) * rinv;

    float mx = lg[0]; int bi = 0;
    #pragma unroll
    for (int k = 1; k < KK; ++k) if (lg[k] > mx) { mx = lg[k]; bi = k; }

    float ex[KK], se = 0.f;
    #pragma unroll
    for (int k = 0; k < KK; ++k) { ex[k] = expf(lg[k] - mx); se += ex[k]; }
    float rse = 1.0f / se;

    const int m = rowbase + n;
    if (h == 0) {
        __builtin_nontemporal_store((float)bi, &out_idx[m]);
        besti[wave][n] = bi;
        nt_store4(&out_log[(size_t)m * KK],     lg[0], lg[1], lg[2], lg[3]);
        nt_store4(&out_log[(size_t)m * KK + 4], lg[4], lg[5], lg[6], lg[7]);
    } else {
        nt_store4(&out_soft[(size_t)m * KK],     ex[0] * rse, ex[1] * rse, ex[2] * rse, ex[3] * rse);
        nt_store4(&out_soft[(size_t)m * KK + 4], ex[4] * rse, ex[5] * rse, ex[6] * rse, ex[7] * rse);
    }

    // ---- embedding: emb[row] = codebook[best[row]], coalesced per wave ----
    // lgkmcnt(0) only: besti visibility; do NOT wait on own output stores
    __builtin_amdgcn_s_waitcnt(0xc07f);
    const float4* cb4 = (const float4*)cb;
    #pragma unroll
    for (int i = 0; i < 16; ++i) {
        int f4 = lane + 64 * i;          // 0..1023 over 32 rows x 32 float4
        int rl = f4 >> 5;
        int c  = f4 & 31;
        int k0 = besti[wave][rl];
        nt_copy4(&out_emb[((size_t)(rowbase + rl) * 32 + c) * 4], &cb4[k0 * 32 + c]);
    }
}

extern "C" void kernel_launch(void* const* d_in, const int* in_sizes, int n_in,
                              void* d_out, int out_size, void* d_ws, size_t ws_size,
                              hipStream_t stream) {
    const float* x     = (const float*)d_in[0];
    const float* W     = (const float*)d_in[1];
    const float* b     = (const float*)d_in[2];
    const float* gamma = (const float*)d_in[3];
    const float* beta  = (const float*)d_in[4];
    const float* cb    = (const float*)d_in[5];
    const int B = in_sizes[0] / DD;

    float*  ws  = (float*)d_ws;
    ushort* wsA = (ushort*)d_ws;

    float* out    = (float*)d_out;
    float* o_idx  = out;
    float* o_soft = out + (size_t)B;
    float* o_emb  = out + (size_t)B * (1 + KK);
    float* o_log  = out + (size_t)B * (1 + KK + DD);

    hipLaunchKernelGGL(l1q_prep, dim3(40), dim3(256), 0, stream, W, b, gamma, beta, cb, wsA, ws);
    const int grid = B / 512;
    hipLaunchKernelGGL(l1q_main, dim3(grid), dim3(1024), 0, stream,
                       x, wsA, ws, cb, o_idx, o_soft, o_emb, o_log, B);
}